// Round 7
// baseline (294.549 us; speedup 1.0000x reference)
//
#include <hip/hip_runtime.h>
#include <math.h>

namespace {

constexpr int B = 2;
constexpr int F = 4096;      // triangles per batch
constexpr int Q = 16384;     // points per batch
constexpr int NP = B * Q;    // 32768 total points
constexpr int NCHUNK = 8;    // triangle chunks
constexpr int CF = F / NCHUNK;  // 512 triangles per chunk
constexpr int BLOCK = 256;

// output layout in d_out (float32): dist [NP], closest [NP,3], faces [NP]
constexpr int OFF_DIST = 0;
constexpr int OFF_CP = NP;
constexpr int OFF_FACE = 4 * NP;

constexpr size_t REC_BYTES = (size_t)B * F * 16 * sizeof(float);   // 512 KiB
constexpr size_t PART_BYTES = (size_t)NCHUNK * NP * sizeof(float); // 1 MiB each

// ---------------- exact path (reference-bit-order, contract OFF) -----------

__device__ __forceinline__ float safediv(float num, float den) {
  #pragma clang fp contract(off)
  float d = (fabsf(den) > 1e-12f) ? den : 1.0f;
  return num / d;
}

__device__ __forceinline__ float clamp01(float x) {
  return fminf(fmaxf(x, 0.0f), 1.0f);
}

// Ericson region-based closest point on triangle, mirroring the JAX reference
// op-for-op (including the where/override order). Contract OFF inside.
__device__ __forceinline__ void closest_pt(
    float px, float py, float pz,
    float ax, float ay, float az,
    float bx, float by, float bz,
    float cx, float cy, float cz,
    float& rx, float& ry, float& rz) {
  #pragma clang fp contract(off)
  float abx = bx - ax, aby = by - ay, abz = bz - az;
  float acx = cx - ax, acy = cy - ay, acz = cz - az;
  float apx = px - ax, apy = py - ay, apz = pz - az;
  float d1 = (abx * apx + aby * apy) + abz * apz;
  float d2 = (acx * apx + acy * apy) + acz * apz;
  float bpx = px - bx, bpy = py - by, bpz = pz - bz;
  float d3 = (abx * bpx + aby * bpy) + abz * bpz;
  float d4 = (acx * bpx + acy * bpy) + acz * bpz;
  float cpx = px - cx, cpy = py - cy, cpz = pz - cz;
  float d5 = (abx * cpx + aby * cpy) + abz * cpz;
  float d6 = (acx * cpx + acy * cpy) + acz * cpz;

  float vc = d1 * d4 - d3 * d2;
  float vb = d5 * d2 - d1 * d6;
  float va = d3 * d6 - d5 * d4;

  float v_ab = clamp01(safediv(d1, d1 - d3));
  float w_ac = clamp01(safediv(d2, d2 - d6));
  float w_bc = clamp01(safediv(d4 - d3, (d4 - d3) + (d5 - d6)));

  float denom = (va + vb) + vc;
  float v = safediv(vb, denom);
  float w = safediv(vc, denom);

  float ox = ax + abx * v + acx * w;
  float oy = ay + aby * v + acy * w;
  float oz = az + abz * v + acz * w;

  bool m_bc = (va <= 0.0f) && (d4 - d3 >= 0.0f) && (d5 - d6 >= 0.0f);
  bool m_ac = (vb <= 0.0f) && (d2 >= 0.0f) && (d6 <= 0.0f);
  bool m_ab = (vc <= 0.0f) && (d1 >= 0.0f) && (d3 <= 0.0f);
  bool m_c  = (d6 >= 0.0f) && (d5 <= d6);
  bool m_b  = (d3 >= 0.0f) && (d4 <= d3);
  bool m_a  = (d1 <= 0.0f) && (d2 <= 0.0f);

  if (m_bc) { ox = bx + w_bc * (cx - bx); oy = by + w_bc * (cy - by); oz = bz + w_bc * (cz - bz); }
  if (m_ac) { ox = ax + w_ac * acx;       oy = ay + w_ac * acy;       oz = az + w_ac * acz; }
  if (m_ab) { ox = ax + v_ab * abx;       oy = ay + v_ab * aby;       oz = az + v_ab * abz; }
  if (m_c)  { ox = cx; oy = cy; oz = cz; }
  if (m_b)  { ox = bx; oy = by; oz = bz; }
  if (m_a)  { ox = ax; oy = ay; oz = az; }

  rx = ox; ry = oy; rz = oz;
}

__device__ __forceinline__ float exact_d2(
    float px, float py, float pz, const float* __restrict__ g /*a,b,c*/) {
  #pragma clang fp contract(off)
  float rx, ry, rz;
  closest_pt(px, py, pz,
             g[0], g[1], g[2], g[3], g[4], g[5], g[6], g[7], g[8],
             rx, ry, rz);
  float dx = px - rx, dy = py - ry, dz = pz - rz;
  return (dx * dx + dy * dy) + dz * dz;
}

// ---------------- prep: 16-float Gram record per triangle ------------------
// rec[i] = [ax,ay,az,abx][aby,abz,acx,acy][acz,aa,bb,abac][raa,rbb,rcc,rdn]

__global__ __launch_bounds__(BLOCK) void bvh_prep(
    const float* __restrict__ tris, float* __restrict__ rec) {
  int i = blockIdx.x * BLOCK + threadIdx.x;
  if (i >= B * F) return;
  const float* g = tris + (size_t)i * 9;
  float ax = g[0], ay = g[1], az = g[2];
  float abx = g[3] - ax, aby = g[4] - ay, abz = g[5] - az;
  float acx = g[6] - ax, acy = g[7] - ay, acz = g[8] - az;
  float aa   = abx * abx + aby * aby + abz * abz;
  float bb   = acx * acx + acy * acy + acz * acz;
  float abac = abx * acx + aby * acy + abz * acz;
  float bcx = acx - abx, bcy = acy - aby, bcz = acz - abz;
  float cc   = bcx * bcx + bcy * bcy + bcz * bcz;
  float nx = aby * acz - abz * acy;
  float ny = abz * acx - abx * acz;
  float nz = abx * acy - aby * acx;
  float n2 = nx * nx + ny * ny + nz * nz;
  float raa = (aa > 1e-12f) ? 1.0f / aa : 1.0f;
  float rbb = (bb > 1e-12f) ? 1.0f / bb : 1.0f;
  float rcc = (cc > 1e-12f) ? 1.0f / cc : 1.0f;
  float rdn = (n2 > 1e-12f) ? 1.0f / n2 : 1.0f;
  float4* r = (float4*)(rec + (size_t)i * 16);
  r[0] = make_float4(ax, ay, az, abx);
  r[1] = make_float4(aby, abz, acx, acy);
  r[2] = make_float4(acz, aa, bb, abac);
  r[3] = make_float4(raa, rbb, rcc, rdn);
}

// ---------------- screen kernel (SMEM records path) ------------------------

__global__ __launch_bounds__(BLOCK, 4) void bvh_partial_smem(
    const float* __restrict__ tris,   // [B, F, 3, 3] (exact tail only)
    const float* __restrict__ pts,    // [B, Q, 3]
    const float* __restrict__ rec,    // [B*F, 16]
    float* __restrict__ dbest,        // [NCHUNK, NP]
    int* __restrict__ ibest) {        // [NCHUNK, NP]
  const int chunk = blockIdx.y;
  const int gpt = blockIdx.x * BLOCK + threadIdx.x;  // 0 .. NP-1
  const int batch = gpt / Q;  // uniform per block (BLOCK divides Q)
  const int tri0 = chunk * CF;
  const float* tb = tris + (size_t)batch * F * 9;
  const float* rb = rec + ((size_t)batch * F + tri0) * 16;  // wave-uniform

  const float px = pts[gpt * 3 + 0];
  const float py = pts[gpt * 3 + 1];
  const float pz = pts[gpt * 3 + 2];

  // sorted top-4 packed keys: key = (bits(d2) & ~0x1FF) | t  (u-int compare
  // == float compare for d2>=0; ties resolve toward lower t = first occur.)
  unsigned K1 = 0xFFFFFFFFu, K2 = 0xFFFFFFFFu, K3 = 0xFFFFFFFFu, K4 = 0xFFFFFFFFu;

  {
    #pragma clang fp contract(fast)
    #pragma unroll 2
    for (int t = 0; t < CF; ++t) {
      const float4* r4 = (const float4*)(rb + (size_t)t * 16);  // uniform addr
      float4 R0 = r4[0], R1 = r4[1], R2 = r4[2], R3 = r4[3];
      float ax = R0.x, ay = R0.y, az = R0.z, abx = R0.w;
      float aby = R1.x, abz = R1.y, acx = R1.z, acy = R1.w;
      float acz = R2.x, aa = R2.y, bb = R2.z, abac = R2.w;
      float raa = R3.x, rbb = R3.y, rcc = R3.z, rdn = R3.w;

      float apx = px - ax, apy = py - ay, apz = pz - az;
      float ap2 = fmaf(apx, apx, fmaf(apy, apy, apz * apz));
      float d1  = fmaf(apx, abx, fmaf(apy, aby, apz * abz));
      float d2  = fmaf(apx, acx, fmaf(apy, acy, apz * acz));
      float d3 = d1 - aa, d6 = d2 - bb, d4 = d2 - abac, d5 = d1 - abac;
      float t43 = d4 - d3, t56 = d5 - d6;
      float va = d3 * d6 - d5 * d4;
      float vb = d5 * d2 - d1 * d6;
      float vc = d1 * d4 - d3 * d2;
      float td1 = d1 + d1, td2 = d2 + d2;

      // interior distance via barycentric quadratic form
      float v = vb * rdn, w = vc * rdn;
      float h1 = fmaf(v, aa, fmaf(w, abac, -td1));
      float h2 = fmaf(w, bb, fmaf(v, abac, -td2));
      float dint = ap2 + fmaf(v, h1, w * h2);

      // three edge-segment distances (exact boundary distance)
      float tab = __builtin_amdgcn_fmed3f(d1 * raa, 0.0f, 1.0f);
      float sab = fmaf(-tab, fmaf(-tab, aa, td1), ap2);
      float tac = __builtin_amdgcn_fmed3f(d2 * rbb, 0.0f, 1.0f);
      float sac = fmaf(-tac, fmaf(-tac, bb, td2), ap2);
      float cc  = t43 + t56;                 // == |bc|^2 identity
      float bp2 = (ap2 - td1) + aa;
      float tbc = __builtin_amdgcn_fmed3f(t43 * rcc, 0.0f, 1.0f);
      float sbc = fmaf(-tbc, fmaf(-tbc, cc, t43 + t43), bp2);

      float dseg = fminf(fminf(sab, sac), sbc);        // v_min3
      float mv   = fminf(fminf(va, vb), vc);           // v_min3
      float d = (mv > 0.0f) ? dint : dseg;
      d = fmaxf(d, 0.0f);                              // keep uint-order valid

      unsigned key = (__float_as_uint(d) & 0xFFFFFE00u) | (unsigned)t;
      bool b1 = key < K1, b2 = key < K2, b3 = key < K3, b4 = key < K4;
      K4 = b3 ? K3 : (b4 ? key : K4);
      K3 = b2 ? K2 : (b3 ? key : K3);
      K2 = b1 ? K1 : (b2 ? key : K2);
      K1 = b1 ? key : K1;
    }
  }

  // candidate indices, sorted ascending (first-occurrence argmin semantics)
  int c0 = (int)(K1 & 0x1FFu), c1 = (int)(K2 & 0x1FFu);
  int c2 = (int)(K3 & 0x1FFu), c3 = (int)(K4 & 0x1FFu);
  int tmp;
  if (c0 > c1) { tmp = c0; c0 = c1; c1 = tmp; }
  if (c2 > c3) { tmp = c2; c2 = c3; c3 = tmp; }
  if (c0 > c2) { tmp = c0; c0 = c2; c2 = tmp; }
  if (c1 > c3) { tmp = c1; c1 = c3; c3 = tmp; }
  if (c1 > c2) { tmp = c1; c1 = c2; c2 = tmp; }

  // exact re-evaluation of the 4 candidates, reference bit order
  float be = exact_d2(px, py, pz, tb + (size_t)(tri0 + c0) * 9);
  int bi = c0;
  { float d = exact_d2(px, py, pz, tb + (size_t)(tri0 + c1) * 9);
    if (d < be) { be = d; bi = c1; } }
  { float d = exact_d2(px, py, pz, tb + (size_t)(tri0 + c2) * 9);
    if (d < be) { be = d; bi = c2; } }
  { float d = exact_d2(px, py, pz, tb + (size_t)(tri0 + c3) * 9);
    if (d < be) { be = d; bi = c3; } }

  dbest[chunk * NP + gpt] = be;
  ibest[chunk * NP + gpt] = tri0 + bi;
}

// ---------------- fallback screen kernel (round-6 proven, LDS path) --------

__global__ __launch_bounds__(BLOCK, 4) void bvh_partial_lds(
    const float* __restrict__ tris,
    const float* __restrict__ pts,
    float* __restrict__ dbest,
    int* __restrict__ ibest) {
  __shared__ float s_tri[CF][20];

  const int chunk = blockIdx.y;
  const int gpt = blockIdx.x * BLOCK + threadIdx.x;
  const int batch = gpt / Q;
  const int tri0 = chunk * CF;
  const float* tb = tris + (size_t)batch * F * 9;

  for (int t = threadIdx.x; t < CF; t += BLOCK) {
    const float* g = tb + (size_t)(tri0 + t) * 9;
    float ax = g[0], ay = g[1], az = g[2];
    float abx = g[3] - ax, aby = g[4] - ay, abz = g[5] - az;
    float acx = g[6] - ax, acy = g[7] - ay, acz = g[8] - az;
    float aa   = abx * abx + aby * aby + abz * abz;
    float bb   = acx * acx + acy * acy + acz * acz;
    float abac = abx * acx + aby * acy + abz * acz;
    float bcx = acx - abx, bcy = acy - aby, bcz = acz - abz;
    float cc   = bcx * bcx + bcy * bcy + bcz * bcz;
    float nx = aby * acz - abz * acy;
    float ny = abz * acx - abx * acz;
    float nz = abx * acy - aby * acx;
    float n2 = nx * nx + ny * ny + nz * nz;
    float raa = (aa > 1e-12f) ? 1.0f / aa : 1.0f;
    float rbb = (bb > 1e-12f) ? 1.0f / bb : 1.0f;
    float rcc = (cc > 1e-12f) ? 1.0f / cc : 1.0f;
    float rdn = (n2 > 1e-12f) ? 1.0f / n2 : 1.0f;
    float c1 = -(ax * abx + ay * aby + az * abz);
    float c2 = -(ax * acx + ay * acy + az * acz);
    float caa2 = ax * ax + ay * ay + az * az;
    float4* s = (float4*)s_tri[t];
    s[0] = make_float4(abx, aby, abz, c1);
    s[1] = make_float4(acx, acy, acz, c2);
    s[2] = make_float4(-2.0f * ax, -2.0f * ay, -2.0f * az, caa2);
    s[3] = make_float4(aa, bb, abac, cc);
    s[4] = make_float4(raa, rbb, rcc, rdn);
  }
  __syncthreads();

  const float px = pts[gpt * 3 + 0];
  const float py = pts[gpt * 3 + 1];
  const float pz = pts[gpt * 3 + 2];

  float m1 = INFINITY, m2 = INFINITY, m3 = INFINITY;
  int i1 = 0, i2 = 0, i3 = 0;
  {
    #pragma clang fp contract(fast)
    #pragma unroll 2
    for (int t = 0; t < CF; ++t) {
      const float4* sv = (const float4*)s_tri[t];
      float4 A0 = sv[0], A1 = sv[1], A2 = sv[2], A3 = sv[3], A4 = sv[4];
      float d1  = fmaf(px, A0.x, fmaf(py, A0.y, fmaf(pz, A0.z, A0.w)));
      float d2  = fmaf(px, A1.x, fmaf(py, A1.y, fmaf(pz, A1.z, A1.w)));
      float ap2 = fmaf(px, A2.x, fmaf(py, A2.y, fmaf(pz, A2.z, A2.w)));
      float aa = A3.x, bb = A3.y, abac = A3.z, cc = A3.w;
      float raa = A4.x, rbb = A4.y, rcc = A4.z, rdn = A4.w;
      float d3 = d1 - aa, d6 = d2 - bb, d4 = d2 - abac, d5 = d1 - abac;
      float va = d3 * d6 - d5 * d4;
      float vb = d5 * d2 - d1 * d6;
      float vc = d1 * d4 - d3 * d2;
      float td1 = d1 + d1, td2 = d2 + d2;
      float v = vb * rdn, w = vc * rdn;
      float h1 = fmaf(v, aa, fmaf(w, abac, -td1));
      float h2 = fmaf(w, bb, fmaf(v, abac, -td2));
      float dint = ap2 + fmaf(v, h1, w * h2);
      float tab = clamp01(d1 * raa);
      float sab = fmaf(-tab, fmaf(-tab, aa, td1), ap2);
      float tac = clamp01(d2 * rbb);
      float sac = fmaf(-tac, fmaf(-tac, bb, td2), ap2);
      float t43 = d4 - d3;
      float bp2 = (ap2 - td1) + aa;
      float tbc = clamp01(t43 * rcc);
      float sbc = fmaf(-tbc, fmaf(-tbc, cc, t43 + t43), bp2);
      float dseg = fminf(fminf(sab, sac), sbc);
      bool inter = (va > 0.0f) & (vb > 0.0f) & (vc > 0.0f);
      float d = inter ? dint : dseg;
      bool b1 = d < m1, b2 = d < m2, b3 = d < m3;
      m3 = b2 ? m2 : (b3 ? d : m3);  i3 = b2 ? i2 : (b3 ? t : i3);
      m2 = b1 ? m1 : (b2 ? d : m2);  i2 = b1 ? i1 : (b2 ? t : i2);
      m1 = b1 ? d  : m1;             i1 = b1 ? t  : i1;
    }
  }

  int ia = i1, ib = i2, ic = i3, tmp;
  if (ia > ib) { tmp = ia; ia = ib; ib = tmp; }
  if (ib > ic) { tmp = ib; ib = ic; ic = tmp; }
  if (ia > ib) { tmp = ia; ia = ib; ib = tmp; }

  float be = exact_d2(px, py, pz, tb + (size_t)(tri0 + ia) * 9);
  int bi = ia;
  { float d = exact_d2(px, py, pz, tb + (size_t)(tri0 + ib) * 9);
    if (d < be) { be = d; bi = ib; } }
  { float d = exact_d2(px, py, pz, tb + (size_t)(tri0 + ic) * 9);
    if (d < be) { be = d; bi = ic; } }

  dbest[chunk * NP + gpt] = be;
  ibest[chunk * NP + gpt] = tri0 + bi;
}

// ---------------- final reduce ---------------------------------------------

__global__ __launch_bounds__(BLOCK) void bvh_reduce(
    const float* __restrict__ tris,
    const float* __restrict__ pts,
    const float* __restrict__ dbest,
    const int* __restrict__ ibest,
    float* __restrict__ out) {
  const int gpt = blockIdx.x * BLOCK + threadIdx.x;
  if (gpt >= NP) return;

  float best = INFINITY;
  int bi = 0;
  for (int c = 0; c < NCHUNK; ++c) {   // ascending chunk order: first-occurrence
    float d = dbest[c * NP + gpt];
    if (d < best) { best = d; bi = ibest[c * NP + gpt]; }
  }

  const int batch = gpt / Q;
  const float px = pts[gpt * 3 + 0];
  const float py = pts[gpt * 3 + 1];
  const float pz = pts[gpt * 3 + 2];

  const float* tr = tris + ((size_t)batch * F + bi) * 9;
  float rx, ry, rz;
  closest_pt(px, py, pz,
             tr[0], tr[1], tr[2],
             tr[3], tr[4], tr[5],
             tr[6], tr[7], tr[8],
             rx, ry, rz);

  out[OFF_DIST + gpt] = best;
  out[OFF_CP + gpt * 3 + 0] = rx;
  out[OFF_CP + gpt * 3 + 1] = ry;
  out[OFF_CP + gpt * 3 + 2] = rz;
  out[OFF_FACE + gpt] = (float)bi;   // harness reads whole out buffer as f32
}

}  // namespace

extern "C" void kernel_launch(void* const* d_in, const int* in_sizes, int n_in,
                              void* d_out, int out_size, void* d_ws, size_t ws_size,
                              hipStream_t stream) {
  const float* tris = (const float*)d_in[0];
  const float* pts  = (const float*)d_in[1];
  float* out = (float*)d_out;

  dim3 grid1(NP / BLOCK, NCHUNK);   // 128 x 8 blocks = 4 blocks/CU
  dim3 grid2((NP + BLOCK - 1) / BLOCK);

  if (ws_size >= REC_BYTES + 2 * PART_BYTES) {
    float* rec   = (float*)d_ws;
    float* dbest = (float*)((char*)d_ws + REC_BYTES);
    int*   ibest = (int*)((char*)d_ws + REC_BYTES + PART_BYTES);
    bvh_prep<<<(B * F + BLOCK - 1) / BLOCK, BLOCK, 0, stream>>>(tris, (float*)rec);
    bvh_partial_smem<<<grid1, BLOCK, 0, stream>>>(tris, pts, rec, dbest, ibest);
    bvh_reduce<<<grid2, BLOCK, 0, stream>>>(tris, pts, dbest, ibest, out);
  } else {
    float* dbest = (float*)d_ws;
    int*   ibest = (int*)((char*)d_ws + PART_BYTES);
    bvh_partial_lds<<<grid1, BLOCK, 0, stream>>>(tris, pts, dbest, ibest);
    bvh_reduce<<<grid2, BLOCK, 0, stream>>>(tris, pts, dbest, ibest, out);
  }
}

// Round 8
// 243.706 us; speedup vs baseline: 1.2086x; 1.2086x over previous
//
#include <hip/hip_runtime.h>
#include <math.h>

namespace {

constexpr int B = 2;
constexpr int F = 4096;      // triangles per batch
constexpr int Q = 16384;     // points per batch
constexpr int NP = B * Q;    // 32768 total points
constexpr int BLOCK = 256;
constexpr int P = 2;         // points per lane

// output layout in d_out (float32): dist [NP], closest [NP,3], faces [NP]
constexpr int OFF_DIST = 0;
constexpr int OFF_CP = NP;
constexpr int OFF_FACE = 4 * NP;

// ---------------- exact path (reference-bit-order, contract OFF) -----------

__device__ __forceinline__ float safediv(float num, float den) {
  #pragma clang fp contract(off)
  float d = (fabsf(den) > 1e-12f) ? den : 1.0f;
  return num / d;
}

__device__ __forceinline__ float clamp01(float x) {
  return fminf(fmaxf(x, 0.0f), 1.0f);
}

// Ericson region-based closest point on triangle, mirroring the JAX reference
// op-for-op (including the where/override order). Contract OFF inside.
__device__ __forceinline__ void closest_pt(
    float px, float py, float pz,
    float ax, float ay, float az,
    float bx, float by, float bz,
    float cx, float cy, float cz,
    float& rx, float& ry, float& rz) {
  #pragma clang fp contract(off)
  float abx = bx - ax, aby = by - ay, abz = bz - az;
  float acx = cx - ax, acy = cy - ay, acz = cz - az;
  float apx = px - ax, apy = py - ay, apz = pz - az;
  float d1 = (abx * apx + aby * apy) + abz * apz;
  float d2 = (acx * apx + acy * apy) + acz * apz;
  float bpx = px - bx, bpy = py - by, bpz = pz - bz;
  float d3 = (abx * bpx + aby * bpy) + abz * bpz;
  float d4 = (acx * bpx + acy * bpy) + acz * bpz;
  float cpx = px - cx, cpy = py - cy, cpz = pz - cz;
  float d5 = (abx * cpx + aby * cpy) + abz * cpz;
  float d6 = (acx * cpx + acy * cpy) + acz * cpz;

  float vc = d1 * d4 - d3 * d2;
  float vb = d5 * d2 - d1 * d6;
  float va = d3 * d6 - d5 * d4;

  float v_ab = clamp01(safediv(d1, d1 - d3));
  float w_ac = clamp01(safediv(d2, d2 - d6));
  float w_bc = clamp01(safediv(d4 - d3, (d4 - d3) + (d5 - d6)));

  float denom = (va + vb) + vc;
  float v = safediv(vb, denom);
  float w = safediv(vc, denom);

  float ox = ax + abx * v + acx * w;
  float oy = ay + aby * v + acy * w;
  float oz = az + abz * v + acz * w;

  bool m_bc = (va <= 0.0f) && (d4 - d3 >= 0.0f) && (d5 - d6 >= 0.0f);
  bool m_ac = (vb <= 0.0f) && (d2 >= 0.0f) && (d6 <= 0.0f);
  bool m_ab = (vc <= 0.0f) && (d1 >= 0.0f) && (d3 <= 0.0f);
  bool m_c  = (d6 >= 0.0f) && (d5 <= d6);
  bool m_b  = (d3 >= 0.0f) && (d4 <= d3);
  bool m_a  = (d1 <= 0.0f) && (d2 <= 0.0f);

  if (m_bc) { ox = bx + w_bc * (cx - bx); oy = by + w_bc * (cy - by); oz = bz + w_bc * (cz - bz); }
  if (m_ac) { ox = ax + w_ac * acx;       oy = ay + w_ac * acy;       oz = az + w_ac * acz; }
  if (m_ab) { ox = ax + v_ab * abx;       oy = ay + v_ab * aby;       oz = az + v_ab * abz; }
  if (m_c)  { ox = cx; oy = cy; oz = cz; }
  if (m_b)  { ox = bx; oy = by; oz = bz; }
  if (m_a)  { ox = ax; oy = ay; oz = az; }

  rx = ox; ry = oy; rz = oz;
}

__device__ __forceinline__ float exact_d2(
    float px, float py, float pz, const float* __restrict__ g /*a,b,c*/) {
  #pragma clang fp contract(off)
  float rx, ry, rz;
  closest_pt(px, py, pz,
             g[0], g[1], g[2], g[3], g[4], g[5], g[6], g[7], g[8],
             rx, ry, rz);
  float dx = px - rx, dy = py - ry, dz = pz - rz;
  return (dx * dx + dy * dy) + dz * dz;
}

// ---------------- fast screen (validated round-7 math, d >= 0) -------------

__device__ __forceinline__ float screen_d2(
    float px, float py, float pz,
    float ax, float ay, float az,
    float abx, float aby, float abz,
    float acx, float acy, float acz,
    float aa, float bb, float abac,
    float raa, float rbb, float rcc, float rdn) {
  #pragma clang fp contract(fast)
  float apx = px - ax, apy = py - ay, apz = pz - az;
  float ap2 = fmaf(apx, apx, fmaf(apy, apy, apz * apz));
  float d1  = fmaf(apx, abx, fmaf(apy, aby, apz * abz));
  float d2  = fmaf(apx, acx, fmaf(apy, acy, apz * acz));
  float d3 = d1 - aa, d6 = d2 - bb, d4 = d2 - abac, d5 = d1 - abac;
  float t43 = d4 - d3, t56 = d5 - d6;
  float va = d3 * d6 - d5 * d4;
  float vb = d5 * d2 - d1 * d6;
  float vc = d1 * d4 - d3 * d2;
  float td1 = d1 + d1, td2 = d2 + d2;

  // interior distance via barycentric quadratic form
  float v = vb * rdn, w = vc * rdn;
  float h1 = fmaf(v, aa, fmaf(w, abac, -td1));
  float h2 = fmaf(w, bb, fmaf(v, abac, -td2));
  float dint = ap2 + fmaf(v, h1, w * h2);

  // three edge-segment distances (exact boundary distance)
  float tab = __builtin_amdgcn_fmed3f(d1 * raa, 0.0f, 1.0f);
  float sab = fmaf(-tab, fmaf(-tab, aa, td1), ap2);
  float tac = __builtin_amdgcn_fmed3f(d2 * rbb, 0.0f, 1.0f);
  float sac = fmaf(-tac, fmaf(-tac, bb, td2), ap2);
  float cc  = t43 + t56;                 // == |bc|^2 identity
  float bp2 = (ap2 - td1) + aa;
  float tbc = __builtin_amdgcn_fmed3f(t43 * rcc, 0.0f, 1.0f);
  float sbc = fmaf(-tbc, fmaf(-tbc, cc, t43 + t43), bp2);

  float dseg = fminf(fminf(sab, sac), sbc);        // v_min3
  float mv   = fminf(fminf(va, vb), vc);           // v_min3
  float d = (mv > 0.0f) ? dint : dseg;
  return fmaxf(d, 0.0f);                           // keep uint-order valid
}

// sorted top-4 packed-key insert (K1<=K2<=K3<=K4 as uints)
__device__ __forceinline__ void ins4(unsigned key,
    unsigned& K1, unsigned& K2, unsigned& K3, unsigned& K4) {
  bool b1 = key < K1, b2 = key < K2, b3 = key < K3, b4 = key < K4;
  K4 = b3 ? K3 : (b4 ? key : K4);
  K3 = b2 ? K2 : (b3 ? key : K3);
  K2 = b1 ? K1 : (b2 ? key : K2);
  K1 = b1 ? key : K1;
}

// exact re-eval of 4 candidates (ascending index, strict <): first-occur argmin
__device__ __forceinline__ void tail4(
    const float* __restrict__ tb, int tri0,
    float px, float py, float pz,
    unsigned K1, unsigned K2, unsigned K3, unsigned K4,
    float& be, int& bi) {
  int c0 = (int)(K1 & 0x1FFu), c1 = (int)(K2 & 0x1FFu);
  int c2 = (int)(K3 & 0x1FFu), c3 = (int)(K4 & 0x1FFu);
  int tmp;
  if (c0 > c1) { tmp = c0; c0 = c1; c1 = tmp; }
  if (c2 > c3) { tmp = c2; c2 = c3; c3 = tmp; }
  if (c0 > c2) { tmp = c0; c0 = c2; c2 = tmp; }
  if (c1 > c3) { tmp = c1; c1 = c3; c3 = tmp; }
  if (c1 > c2) { tmp = c1; c1 = c2; c2 = tmp; }
  be = exact_d2(px, py, pz, tb + (size_t)(tri0 + c0) * 9);
  bi = c0;
  { float d = exact_d2(px, py, pz, tb + (size_t)(tri0 + c1) * 9);
    if (d < be) { be = d; bi = c1; } }
  { float d = exact_d2(px, py, pz, tb + (size_t)(tri0 + c2) * 9);
    if (d < be) { be = d; bi = c2; } }
  { float d = exact_d2(px, py, pz, tb + (size_t)(tri0 + c3) * 9);
    if (d < be) { be = d; bi = c3; } }
}

// ---------------- screen kernel: LDS records, P=2 points/lane --------------
// LDS layout SoA-by-quadword: s_rec[k*CF + t], k=0..3
//  R0=[ax,ay,az,abx] R1=[aby,abz,acx,acy] R2=[acz,aa,bb,abac] R3=[raa,rbb,rcc,rdn]

template <int NC>
__global__ __launch_bounds__(BLOCK, 4) void bvh_partial_p2(
    const float* __restrict__ tris,   // [B, F, 3, 3]
    const float* __restrict__ pts,    // [B, Q, 3]
    float* __restrict__ dbest,        // [NC, NP]
    unsigned short* __restrict__ ibest) {  // [NC, NP], per-batch tri idx
  constexpr int CFL = F / NC;
  __shared__ float4 s_rec[4 * CFL];

  constexpr int BPB = (Q / P) / BLOCK;           // blocks per batch (32)
  const int batch = blockIdx.x / BPB;            // uniform per block
  const int j = (blockIdx.x % BPB) * BLOCK + threadIdx.x;  // 0 .. Q/P-1
  const int chunk = blockIdx.y;
  const int tri0 = chunk * CFL;
  const float* tb = tris + (size_t)batch * F * 9;

  // stage 16-float Gram records into LDS
  for (int t = threadIdx.x; t < CFL; t += BLOCK) {
    const float* g = tb + (size_t)(tri0 + t) * 9;
    float ax = g[0], ay = g[1], az = g[2];
    float abx = g[3] - ax, aby = g[4] - ay, abz = g[5] - az;
    float acx = g[6] - ax, acy = g[7] - ay, acz = g[8] - az;
    float aa   = abx * abx + aby * aby + abz * abz;
    float bb   = acx * acx + acy * acy + acz * acz;
    float abac = abx * acx + aby * acy + abz * acz;
    float bcx = acx - abx, bcy = acy - aby, bcz = acz - abz;
    float cc   = bcx * bcx + bcy * bcy + bcz * bcz;
    float nx = aby * acz - abz * acy;
    float ny = abz * acx - abx * acz;
    float nz = abx * acy - aby * acx;
    float n2 = nx * nx + ny * ny + nz * nz;
    float raa = (aa > 1e-12f) ? 1.0f / aa : 1.0f;     // safediv-style guards
    float rbb = (bb > 1e-12f) ? 1.0f / bb : 1.0f;
    float rcc = (cc > 1e-12f) ? 1.0f / cc : 1.0f;
    float rdn = (n2 > 1e-12f) ? 1.0f / n2 : 1.0f;
    s_rec[0 * CFL + t] = make_float4(ax, ay, az, abx);
    s_rec[1 * CFL + t] = make_float4(aby, abz, acx, acy);
    s_rec[2 * CFL + t] = make_float4(acz, aa, bb, abac);
    s_rec[3 * CFL + t] = make_float4(raa, rbb, rcc, rdn);
  }
  __syncthreads();

  const int p0 = batch * Q + j;
  const int p1 = p0 + Q / P;
  const float px0 = pts[p0 * 3 + 0], py0 = pts[p0 * 3 + 1], pz0 = pts[p0 * 3 + 2];
  const float px1 = pts[p1 * 3 + 0], py1 = pts[p1 * 3 + 1], pz1 = pts[p1 * 3 + 2];

  unsigned A1 = ~0u, A2 = ~0u, A3 = ~0u, A4 = ~0u;   // top-4 for point 0
  unsigned B1 = ~0u, B2 = ~0u, B3 = ~0u, B4 = ~0u;   // top-4 for point 1

  for (int t = 0; t < CFL; ++t) {
    const float4 R0 = s_rec[0 * CFL + t];   // uniform addr -> broadcast
    const float4 R1 = s_rec[1 * CFL + t];
    const float4 R2 = s_rec[2 * CFL + t];
    const float4 R3 = s_rec[3 * CFL + t];
    float ax = R0.x, ay = R0.y, az = R0.z, abx = R0.w;
    float aby = R1.x, abz = R1.y, acx = R1.z, acy = R1.w;
    float acz = R2.x, aa = R2.y, bb = R2.z, abac = R2.w;
    float raa = R3.x, rbb = R3.y, rcc = R3.z, rdn = R3.w;

    float d0 = screen_d2(px0, py0, pz0, ax, ay, az, abx, aby, abz,
                         acx, acy, acz, aa, bb, abac, raa, rbb, rcc, rdn);
    ins4((__float_as_uint(d0) & 0xFFFFFE00u) | (unsigned)t, A1, A2, A3, A4);

    float d1 = screen_d2(px1, py1, pz1, ax, ay, az, abx, aby, abz,
                         acx, acy, acz, aa, bb, abac, raa, rbb, rcc, rdn);
    ins4((__float_as_uint(d1) & 0xFFFFFE00u) | (unsigned)t, B1, B2, B3, B4);
  }

  float be0, be1;
  int bi0, bi1;
  tail4(tb, tri0, px0, py0, pz0, A1, A2, A3, A4, be0, bi0);
  tail4(tb, tri0, px1, py1, pz1, B1, B2, B3, B4, be1, bi1);

  dbest[chunk * NP + p0] = be0;
  ibest[chunk * NP + p0] = (unsigned short)(tri0 + bi0);
  dbest[chunk * NP + p1] = be1;
  ibest[chunk * NP + p1] = (unsigned short)(tri0 + bi1);
}

// ---------------- final reduce ---------------------------------------------

template <int NC>
__global__ __launch_bounds__(BLOCK) void bvh_reduce(
    const float* __restrict__ tris,
    const float* __restrict__ pts,
    const float* __restrict__ dbest,
    const unsigned short* __restrict__ ibest,
    float* __restrict__ out) {
  const int gpt = blockIdx.x * BLOCK + threadIdx.x;
  if (gpt >= NP) return;

  float best = INFINITY;
  int bi = 0;
  for (int c = 0; c < NC; ++c) {   // ascending chunk order: first-occurrence
    float d = dbest[c * NP + gpt];
    if (d < best) { best = d; bi = ibest[c * NP + gpt]; }
  }

  const int batch = gpt / Q;
  const float px = pts[gpt * 3 + 0];
  const float py = pts[gpt * 3 + 1];
  const float pz = pts[gpt * 3 + 2];

  const float* tr = tris + ((size_t)batch * F + bi) * 9;
  float rx, ry, rz;
  closest_pt(px, py, pz,
             tr[0], tr[1], tr[2],
             tr[3], tr[4], tr[5],
             tr[6], tr[7], tr[8],
             rx, ry, rz);

  out[OFF_DIST + gpt] = best;
  out[OFF_CP + gpt * 3 + 0] = rx;
  out[OFF_CP + gpt * 3 + 1] = ry;
  out[OFF_CP + gpt * 3 + 2] = rz;
  out[OFF_FACE + gpt] = (float)bi;   // per-batch face idx, as f32
}

}  // namespace

extern "C" void kernel_launch(void* const* d_in, const int* in_sizes, int n_in,
                              void* d_out, int out_size, void* d_ws, size_t ws_size,
                              hipStream_t stream) {
  const float* tris = (const float*)d_in[0];
  const float* pts  = (const float*)d_in[1];
  float* out = (float*)d_out;

  dim3 grid2((NP + BLOCK - 1) / BLOCK);
  const int gx = B * ((Q / P) / BLOCK);   // 64 blocks in x

  constexpr size_t NC16_BYTES = (size_t)16 * NP * (sizeof(float) + sizeof(unsigned short));
  constexpr size_t NC8_BYTES  = (size_t)8  * NP * (sizeof(float) + sizeof(unsigned short));

  if (ws_size >= NC16_BYTES) {
    float* dbest = (float*)d_ws;
    unsigned short* ibest = (unsigned short*)((char*)d_ws + (size_t)16 * NP * sizeof(float));
    bvh_partial_p2<16><<<dim3(gx, 16), BLOCK, 0, stream>>>(tris, pts, dbest, ibest);
    bvh_reduce<16><<<grid2, BLOCK, 0, stream>>>(tris, pts, dbest, ibest, out);
  } else if (ws_size >= NC8_BYTES) {
    float* dbest = (float*)d_ws;
    unsigned short* ibest = (unsigned short*)((char*)d_ws + (size_t)8 * NP * sizeof(float));
    bvh_partial_p2<8><<<dim3(gx, 8), BLOCK, 0, stream>>>(tris, pts, dbest, ibest);
    bvh_reduce<8><<<grid2, BLOCK, 0, stream>>>(tris, pts, dbest, ibest, out);
  } else {
    float* dbest = (float*)d_ws;
    unsigned short* ibest = (unsigned short*)((char*)d_ws + (size_t)4 * NP * sizeof(float));
    bvh_partial_p2<4><<<dim3(gx, 4), BLOCK, 0, stream>>>(tris, pts, dbest, ibest);
    bvh_reduce<4><<<grid2, BLOCK, 0, stream>>>(tris, pts, dbest, ibest, out);
  }
}

// Round 9
// 199.529 us; speedup vs baseline: 1.4762x; 1.2214x over previous
//
#include <hip/hip_runtime.h>
#include <math.h>

namespace {

typedef float v2f __attribute__((ext_vector_type(2)));

constexpr int B = 2;
constexpr int F = 4096;      // triangles per batch
constexpr int Q = 16384;     // points per batch
constexpr int NP = B * Q;    // 32768 total points
constexpr int BLOCK = 256;
constexpr int P = 2;         // points per lane in screen

// output layout in d_out (float32): dist [NP], closest [NP,3], faces [NP]
constexpr int OFF_DIST = 0;
constexpr int OFF_CP = NP;
constexpr int OFF_FACE = 4 * NP;

// ---------------- exact path (reference-bit-order, contract OFF) -----------

__device__ __forceinline__ float safediv(float num, float den) {
  #pragma clang fp contract(off)
  float d = (fabsf(den) > 1e-12f) ? den : 1.0f;
  return num / d;
}

__device__ __forceinline__ float clamp01(float x) {
  return fminf(fmaxf(x, 0.0f), 1.0f);
}

// Ericson region-based closest point on triangle, mirroring the JAX reference
// op-for-op (including the where/override order). Contract OFF inside.
__device__ __forceinline__ void closest_pt(
    float px, float py, float pz,
    float ax, float ay, float az,
    float bx, float by, float bz,
    float cx, float cy, float cz,
    float& rx, float& ry, float& rz) {
  #pragma clang fp contract(off)
  float abx = bx - ax, aby = by - ay, abz = bz - az;
  float acx = cx - ax, acy = cy - ay, acz = cz - az;
  float apx = px - ax, apy = py - ay, apz = pz - az;
  float d1 = (abx * apx + aby * apy) + abz * apz;
  float d2 = (acx * apx + acy * apy) + acz * apz;
  float bpx = px - bx, bpy = py - by, bpz = pz - bz;
  float d3 = (abx * bpx + aby * bpy) + abz * bpz;
  float d4 = (acx * bpx + acy * bpy) + acz * bpz;
  float cpx = px - cx, cpy = py - cy, cpz = pz - cz;
  float d5 = (abx * cpx + aby * cpy) + abz * cpz;
  float d6 = (acx * cpx + acy * cpy) + acz * cpz;

  float vc = d1 * d4 - d3 * d2;
  float vb = d5 * d2 - d1 * d6;
  float va = d3 * d6 - d5 * d4;

  float v_ab = clamp01(safediv(d1, d1 - d3));
  float w_ac = clamp01(safediv(d2, d2 - d6));
  float w_bc = clamp01(safediv(d4 - d3, (d4 - d3) + (d5 - d6)));

  float denom = (va + vb) + vc;
  float v = safediv(vb, denom);
  float w = safediv(vc, denom);

  float ox = ax + abx * v + acx * w;
  float oy = ay + aby * v + acy * w;
  float oz = az + abz * v + acz * w;

  bool m_bc = (va <= 0.0f) && (d4 - d3 >= 0.0f) && (d5 - d6 >= 0.0f);
  bool m_ac = (vb <= 0.0f) && (d2 >= 0.0f) && (d6 <= 0.0f);
  bool m_ab = (vc <= 0.0f) && (d1 >= 0.0f) && (d3 <= 0.0f);
  bool m_c  = (d6 >= 0.0f) && (d5 <= d6);
  bool m_b  = (d3 >= 0.0f) && (d4 <= d3);
  bool m_a  = (d1 <= 0.0f) && (d2 <= 0.0f);

  if (m_bc) { ox = bx + w_bc * (cx - bx); oy = by + w_bc * (cy - by); oz = bz + w_bc * (cz - bz); }
  if (m_ac) { ox = ax + w_ac * acx;       oy = ay + w_ac * acy;       oz = az + w_ac * acz; }
  if (m_ab) { ox = ax + v_ab * abx;       oy = ay + v_ab * aby;       oz = az + v_ab * abz; }
  if (m_c)  { ox = cx; oy = cy; oz = cz; }
  if (m_b)  { ox = bx; oy = by; oz = bz; }
  if (m_a)  { ox = ax; oy = ay; oz = az; }

  rx = ox; ry = oy; rz = oz;
}

__device__ __forceinline__ float exact_d2(
    float px, float py, float pz, const float* __restrict__ g /*a,b,c*/) {
  #pragma clang fp contract(off)
  float rx, ry, rz;
  closest_pt(px, py, pz,
             g[0], g[1], g[2], g[3], g[4], g[5], g[6], g[7], g[8],
             rx, ry, rz);
  float dx = px - rx, dy = py - ry, dz = pz - rz;
  return (dx * dx + dy * dy) + dz * dz;
}

// ---------------- sorted top-k packed-key inserts --------------------------

__device__ __forceinline__ void ins4(unsigned key,
    unsigned& K1, unsigned& K2, unsigned& K3, unsigned& K4) {
  bool b1 = key < K1, b2 = key < K2, b3 = key < K3, b4 = key < K4;
  K4 = b3 ? K3 : (b4 ? key : K4);
  K3 = b2 ? K2 : (b3 ? key : K3);
  K2 = b1 ? K1 : (b2 ? key : K2);
  K1 = b1 ? key : K1;
}

__device__ __forceinline__ void ins8(unsigned key,
    unsigned& K1, unsigned& K2, unsigned& K3, unsigned& K4,
    unsigned& K5, unsigned& K6, unsigned& K7, unsigned& K8) {
  bool b1 = key < K1, b2 = key < K2, b3 = key < K3, b4 = key < K4;
  bool b5 = key < K5, b6 = key < K6, b7 = key < K7, b8 = key < K8;
  K8 = b7 ? K7 : (b8 ? key : K8);
  K7 = b6 ? K6 : (b7 ? key : K7);
  K6 = b5 ? K5 : (b6 ? key : K6);
  K5 = b4 ? K4 : (b5 ? key : K5);
  K4 = b3 ? K3 : (b4 ? key : K4);
  K3 = b2 ? K2 : (b3 ? key : K3);
  K2 = b1 ? K1 : (b2 ? key : K2);
  K1 = b1 ? key : K1;
}

// ---------------- new path: screen (packed fp32) + finish ------------------
// LDS record (20 floats = 5 quads):
//  R0=[abx,aby,abz,c1] R1=[acx,acy,acz,c2] R2=[-2ax,-2ay,-2az,|a|^2]
//  R3=[aa,bb,abac,cc]  R4=[raa,rbb,rcc,rdn]
// c1=-(a.ab), c2=-(a.ac). Screen works on d^2 - |p|^2; |p|^2 restored before
// key packing so d>=0 keeps uint order valid.

// scalar per-point finish of the screen: returns packed key
__device__ __forceinline__ unsigned screen_fin(
    float dint, float tabm, float tacm, float tbcm,
    float td1, float td2, float ap2m, float bp2, float t43d,
    float va, float vb, float vc,
    float aa, float bb, float cc, float pp, int idx) {
  float tab = __builtin_amdgcn_fmed3f(tabm, 0.0f, 1.0f);
  float sab = fmaf(-tab, fmaf(-tab, aa, td1), ap2m);
  float tac = __builtin_amdgcn_fmed3f(tacm, 0.0f, 1.0f);
  float sac = fmaf(-tac, fmaf(-tac, bb, td2), ap2m);
  float tbc = __builtin_amdgcn_fmed3f(tbcm, 0.0f, 1.0f);
  float sbc = fmaf(-tbc, fmaf(-tbc, cc, t43d), bp2);
  float dseg = fminf(fminf(sab, sac), sbc);        // v_min3
  float mv   = fminf(fminf(va, vb), vc);           // v_min3
  float d = (mv > 0.0f) ? dint : dseg;
  d = fmaxf(d + pp, 0.0f);                         // restore |p|^2, keep >=0
  return (__float_as_uint(d) & 0xFFFFF000u) | (unsigned)idx;
}

template <int NC>
__global__ __launch_bounds__(BLOCK, 4) void bvh_screen(
    const float* __restrict__ tris,   // [B, F, 3, 3]
    const float* __restrict__ pts,    // [B, Q, 3]
    uint4* __restrict__ keys) {       // [NC, NP]
  constexpr int CFL = F / NC;
  __shared__ float4 s_rec[5 * CFL];

  constexpr int BPB = (Q / P) / BLOCK;
  const int batch = blockIdx.x / BPB;            // uniform per block
  const int j = (blockIdx.x % BPB) * BLOCK + threadIdx.x;
  const int chunk = blockIdx.y;
  const int tri0 = chunk * CFL;
  const float* tb = tris + (size_t)batch * F * 9;

  for (int t = threadIdx.x; t < CFL; t += BLOCK) {
    const float* g = tb + (size_t)(tri0 + t) * 9;
    float ax = g[0], ay = g[1], az = g[2];
    float abx = g[3] - ax, aby = g[4] - ay, abz = g[5] - az;
    float acx = g[6] - ax, acy = g[7] - ay, acz = g[8] - az;
    float aa   = abx * abx + aby * aby + abz * abz;
    float bb   = acx * acx + acy * acy + acz * acz;
    float abac = abx * acx + aby * acy + abz * acz;
    float bcx = acx - abx, bcy = acy - aby, bcz = acz - abz;
    float cc   = bcx * bcx + bcy * bcy + bcz * bcz;
    float nx = aby * acz - abz * acy;
    float ny = abz * acx - abx * acz;
    float nz = abx * acy - aby * acx;
    float n2 = nx * nx + ny * ny + nz * nz;
    float raa = (aa > 1e-12f) ? 1.0f / aa : 1.0f;     // safediv-style guards
    float rbb = (bb > 1e-12f) ? 1.0f / bb : 1.0f;
    float rcc = (cc > 1e-12f) ? 1.0f / cc : 1.0f;
    float rdn = (n2 > 1e-12f) ? 1.0f / n2 : 1.0f;
    float c1 = -(ax * abx + ay * aby + az * abz);
    float c2 = -(ax * acx + ay * acy + az * acz);
    float caa2 = ax * ax + ay * ay + az * az;
    s_rec[0 * CFL + t] = make_float4(abx, aby, abz, c1);
    s_rec[1 * CFL + t] = make_float4(acx, acy, acz, c2);
    s_rec[2 * CFL + t] = make_float4(-2.0f * ax, -2.0f * ay, -2.0f * az, caa2);
    s_rec[3 * CFL + t] = make_float4(aa, bb, abac, cc);
    s_rec[4 * CFL + t] = make_float4(raa, rbb, rcc, rdn);
  }
  __syncthreads();

  const int p0 = batch * Q + j;
  const int p1 = p0 + Q / P;
  const float px0 = pts[p0 * 3 + 0], py0 = pts[p0 * 3 + 1], pz0 = pts[p0 * 3 + 2];
  const float px1 = pts[p1 * 3 + 0], py1 = pts[p1 * 3 + 1], pz1 = pts[p1 * 3 + 2];
  const v2f pxv = {px0, px1};
  const v2f pyv = {py0, py1};
  const v2f pzv = {pz0, pz1};
  const float pp0 = px0 * px0 + py0 * py0 + pz0 * pz0;
  const float pp1 = px1 * px1 + py1 * py1 + pz1 * pz1;

  unsigned A1 = ~0u, A2 = ~0u, A3 = ~0u, A4 = ~0u;
  unsigned Bk1 = ~0u, Bk2 = ~0u, Bk3 = ~0u, Bk4 = ~0u;

  {
    #pragma clang fp contract(fast)
    for (int t = 0; t < CFL; ++t) {
      const float4 R0 = s_rec[0 * CFL + t];   // uniform addr -> broadcast
      const float4 R1 = s_rec[1 * CFL + t];
      const float4 R2 = s_rec[2 * CFL + t];
      const float4 R3 = s_rec[3 * CFL + t];
      const float4 R4 = s_rec[4 * CFL + t];

      // packed (both points per instruction)
      v2f d1   = pxv * R0.x + pyv * R0.y + pzv * R0.z + R0.w;   // ap.ab
      v2f d2   = pxv * R1.x + pyv * R1.y + pzv * R1.z + R1.w;   // ap.ac
      v2f ap2m = pxv * R2.x + pyv * R2.y + pzv * R2.z + R2.w;   // |ap|^2-|p|^2
      v2f d3 = d1 - R3.x, d6 = d2 - R3.y, d4 = d2 - R3.z, d5 = d1 - R3.z;
      v2f t43 = d4 - d3;
      v2f va = d3 * d6 - d5 * d4;
      v2f vb = d5 * d2 - d1 * d6;
      v2f vc = d1 * d4 - d3 * d2;
      v2f td1 = d1 + d1, td2 = d2 + d2;
      v2f v = vb * R4.w, w = vc * R4.w;
      v2f h1 = v * R3.x + (w * R3.z - td1);
      v2f h2 = w * R3.y + (v * R3.z - td2);
      v2f dint = ap2m + (v * h1 + w * h2);
      v2f tabm = d1 * R4.x, tacm = d2 * R4.y, tbcm = t43 * R4.z;
      v2f bp2 = (ap2m - td1) + R3.x;
      v2f t43d = t43 + t43;

      unsigned kA = screen_fin(dint.x, tabm.x, tacm.x, tbcm.x,
                               td1.x, td2.x, ap2m.x, bp2.x, t43d.x,
                               va.x, vb.x, vc.x,
                               R3.x, R3.y, R3.w, pp0, tri0 + t);
      ins4(kA, A1, A2, A3, A4);
      unsigned kB = screen_fin(dint.y, tabm.y, tacm.y, tbcm.y,
                               td1.y, td2.y, ap2m.y, bp2.y, t43d.y,
                               va.y, vb.y, vc.y,
                               R3.x, R3.y, R3.w, pp1, tri0 + t);
      ins4(kB, Bk1, Bk2, Bk3, Bk4);
    }
  }

  keys[(size_t)chunk * NP + p0] = make_uint4(A1, A2, A3, A4);
  keys[(size_t)chunk * NP + p1] = make_uint4(Bk1, Bk2, Bk3, Bk4);
}

template <int NC>
__global__ __launch_bounds__(BLOCK) void bvh_finish(
    const float* __restrict__ tris,
    const float* __restrict__ pts,
    const uint4* __restrict__ keys,
    float* __restrict__ out) {
  const int gpt = blockIdx.x * BLOCK + threadIdx.x;
  if (gpt >= NP) return;

  unsigned K1 = ~0u, K2 = ~0u, K3 = ~0u, K4 = ~0u;
  unsigned K5 = ~0u, K6 = ~0u, K7 = ~0u, K8 = ~0u;
  for (int c = 0; c < NC; ++c) {
    uint4 k = keys[(size_t)c * NP + gpt];
    ins8(k.x, K1, K2, K3, K4, K5, K6, K7, K8);
    ins8(k.y, K1, K2, K3, K4, K5, K6, K7, K8);
    ins8(k.z, K1, K2, K3, K4, K5, K6, K7, K8);
    ins8(k.w, K1, K2, K3, K4, K5, K6, K7, K8);
  }

  const int batch = gpt / Q;
  const float* tb = tris + (size_t)batch * F * 9;
  const float px = pts[gpt * 3 + 0];
  const float py = pts[gpt * 3 + 1];
  const float pz = pts[gpt * 3 + 2];

  // order-independent first-occurrence argmin over the 8 candidates
  float be = INFINITY;
  int bi = 0x7FFFFFFF;
  #define CAND(Kx) { int t_ = (int)(Kx & 0xFFFu); \
    float d_ = exact_d2(px, py, pz, tb + (size_t)t_ * 9); \
    if (d_ < be || (d_ == be && t_ < bi)) { be = d_; bi = t_; } }
  CAND(K1) CAND(K2) CAND(K3) CAND(K4) CAND(K5) CAND(K6) CAND(K7) CAND(K8)
  #undef CAND

  const float* tr = tb + (size_t)bi * 9;
  float rx, ry, rz;
  closest_pt(px, py, pz,
             tr[0], tr[1], tr[2], tr[3], tr[4], tr[5], tr[6], tr[7], tr[8],
             rx, ry, rz);

  out[OFF_DIST + gpt] = be;
  out[OFF_CP + gpt * 3 + 0] = rx;
  out[OFF_CP + gpt * 3 + 1] = ry;
  out[OFF_CP + gpt * 3 + 2] = rz;
  out[OFF_FACE + gpt] = (float)bi;
}

// ---------------- fallback: round-8 proven path (ws < 8 MiB) ---------------

__device__ __forceinline__ float screen_d2_sc(
    float px, float py, float pz,
    float ax, float ay, float az,
    float abx, float aby, float abz,
    float acx, float acy, float acz,
    float aa, float bb, float abac,
    float raa, float rbb, float rcc, float rdn) {
  #pragma clang fp contract(fast)
  float apx = px - ax, apy = py - ay, apz = pz - az;
  float ap2 = fmaf(apx, apx, fmaf(apy, apy, apz * apz));
  float d1  = fmaf(apx, abx, fmaf(apy, aby, apz * abz));
  float d2  = fmaf(apx, acx, fmaf(apy, acy, apz * acz));
  float d3 = d1 - aa, d6 = d2 - bb, d4 = d2 - abac, d5 = d1 - abac;
  float t43 = d4 - d3, t56 = d5 - d6;
  float va = d3 * d6 - d5 * d4;
  float vb = d5 * d2 - d1 * d6;
  float vc = d1 * d4 - d3 * d2;
  float td1 = d1 + d1, td2 = d2 + d2;
  float v = vb * rdn, w = vc * rdn;
  float h1 = fmaf(v, aa, fmaf(w, abac, -td1));
  float h2 = fmaf(w, bb, fmaf(v, abac, -td2));
  float dint = ap2 + fmaf(v, h1, w * h2);
  float tab = __builtin_amdgcn_fmed3f(d1 * raa, 0.0f, 1.0f);
  float sab = fmaf(-tab, fmaf(-tab, aa, td1), ap2);
  float tac = __builtin_amdgcn_fmed3f(d2 * rbb, 0.0f, 1.0f);
  float sac = fmaf(-tac, fmaf(-tac, bb, td2), ap2);
  float cc  = t43 + t56;
  float bp2 = (ap2 - td1) + aa;
  float tbc = __builtin_amdgcn_fmed3f(t43 * rcc, 0.0f, 1.0f);
  float sbc = fmaf(-tbc, fmaf(-tbc, cc, t43 + t43), bp2);
  float dseg = fminf(fminf(sab, sac), sbc);
  float mv   = fminf(fminf(va, vb), vc);
  float d = (mv > 0.0f) ? dint : dseg;
  return fmaxf(d, 0.0f);
}

__device__ __forceinline__ void tail4(
    const float* __restrict__ tb, int tri0,
    float px, float py, float pz,
    unsigned K1, unsigned K2, unsigned K3, unsigned K4,
    float& be, int& bi) {
  int c0 = (int)(K1 & 0x1FFu), c1 = (int)(K2 & 0x1FFu);
  int c2 = (int)(K3 & 0x1FFu), c3 = (int)(K4 & 0x1FFu);
  int tmp;
  if (c0 > c1) { tmp = c0; c0 = c1; c1 = tmp; }
  if (c2 > c3) { tmp = c2; c2 = c3; c3 = tmp; }
  if (c0 > c2) { tmp = c0; c0 = c2; c2 = tmp; }
  if (c1 > c3) { tmp = c1; c1 = c3; c3 = tmp; }
  if (c1 > c2) { tmp = c1; c1 = c2; c2 = tmp; }
  be = exact_d2(px, py, pz, tb + (size_t)(tri0 + c0) * 9);
  bi = c0;
  { float d = exact_d2(px, py, pz, tb + (size_t)(tri0 + c1) * 9);
    if (d < be) { be = d; bi = c1; } }
  { float d = exact_d2(px, py, pz, tb + (size_t)(tri0 + c2) * 9);
    if (d < be) { be = d; bi = c2; } }
  { float d = exact_d2(px, py, pz, tb + (size_t)(tri0 + c3) * 9);
    if (d < be) { be = d; bi = c3; } }
}

template <int NC>
__global__ __launch_bounds__(BLOCK, 4) void bvh_partial_p2(
    const float* __restrict__ tris,
    const float* __restrict__ pts,
    float* __restrict__ dbest,
    unsigned short* __restrict__ ibest) {
  constexpr int CFL = F / NC;
  __shared__ float4 s_rec[4 * CFL];

  constexpr int BPB = (Q / P) / BLOCK;
  const int batch = blockIdx.x / BPB;
  const int j = (blockIdx.x % BPB) * BLOCK + threadIdx.x;
  const int chunk = blockIdx.y;
  const int tri0 = chunk * CFL;
  const float* tb = tris + (size_t)batch * F * 9;

  for (int t = threadIdx.x; t < CFL; t += BLOCK) {
    const float* g = tb + (size_t)(tri0 + t) * 9;
    float ax = g[0], ay = g[1], az = g[2];
    float abx = g[3] - ax, aby = g[4] - ay, abz = g[5] - az;
    float acx = g[6] - ax, acy = g[7] - ay, acz = g[8] - az;
    float aa   = abx * abx + aby * aby + abz * abz;
    float bb   = acx * acx + acy * acy + acz * acz;
    float abac = abx * acx + aby * acy + abz * acz;
    float bcx = acx - abx, bcy = acy - aby, bcz = acz - abz;
    float cc   = bcx * bcx + bcy * bcy + bcz * bcz;
    float nx = aby * acz - abz * acy;
    float ny = abz * acx - abx * acz;
    float nz = abx * acy - aby * acx;
    float n2 = nx * nx + ny * ny + nz * nz;
    float raa = (aa > 1e-12f) ? 1.0f / aa : 1.0f;
    float rbb = (bb > 1e-12f) ? 1.0f / bb : 1.0f;
    float rcc = (cc > 1e-12f) ? 1.0f / cc : 1.0f;
    float rdn = (n2 > 1e-12f) ? 1.0f / n2 : 1.0f;
    s_rec[0 * CFL + t] = make_float4(ax, ay, az, abx);
    s_rec[1 * CFL + t] = make_float4(aby, abz, acx, acy);
    s_rec[2 * CFL + t] = make_float4(acz, aa, bb, abac);
    s_rec[3 * CFL + t] = make_float4(raa, rbb, rcc, rdn);
  }
  __syncthreads();

  const int p0 = batch * Q + j;
  const int p1 = p0 + Q / P;
  const float px0 = pts[p0 * 3 + 0], py0 = pts[p0 * 3 + 1], pz0 = pts[p0 * 3 + 2];
  const float px1 = pts[p1 * 3 + 0], py1 = pts[p1 * 3 + 1], pz1 = pts[p1 * 3 + 2];

  unsigned A1 = ~0u, A2 = ~0u, A3 = ~0u, A4 = ~0u;
  unsigned B1 = ~0u, B2 = ~0u, B3 = ~0u, B4 = ~0u;

  for (int t = 0; t < CFL; ++t) {
    const float4 R0 = s_rec[0 * CFL + t];
    const float4 R1 = s_rec[1 * CFL + t];
    const float4 R2 = s_rec[2 * CFL + t];
    const float4 R3 = s_rec[3 * CFL + t];
    float ax = R0.x, ay = R0.y, az = R0.z, abx = R0.w;
    float aby = R1.x, abz = R1.y, acx = R1.z, acy = R1.w;
    float acz = R2.x, aa = R2.y, bb = R2.z, abac = R2.w;
    float raa = R3.x, rbb = R3.y, rcc = R3.z, rdn = R3.w;

    float d0 = screen_d2_sc(px0, py0, pz0, ax, ay, az, abx, aby, abz,
                            acx, acy, acz, aa, bb, abac, raa, rbb, rcc, rdn);
    ins4((__float_as_uint(d0) & 0xFFFFFE00u) | (unsigned)t, A1, A2, A3, A4);
    float d1 = screen_d2_sc(px1, py1, pz1, ax, ay, az, abx, aby, abz,
                            acx, acy, acz, aa, bb, abac, raa, rbb, rcc, rdn);
    ins4((__float_as_uint(d1) & 0xFFFFFE00u) | (unsigned)t, B1, B2, B3, B4);
  }

  float be0, be1;
  int bi0, bi1;
  tail4(tb, tri0, px0, py0, pz0, A1, A2, A3, A4, be0, bi0);
  tail4(tb, tri0, px1, py1, pz1, B1, B2, B3, B4, be1, bi1);

  dbest[chunk * NP + p0] = be0;
  ibest[chunk * NP + p0] = (unsigned short)(tri0 + bi0);
  dbest[chunk * NP + p1] = be1;
  ibest[chunk * NP + p1] = (unsigned short)(tri0 + bi1);
}

template <int NC>
__global__ __launch_bounds__(BLOCK) void bvh_reduce(
    const float* __restrict__ tris,
    const float* __restrict__ pts,
    const float* __restrict__ dbest,
    const unsigned short* __restrict__ ibest,
    float* __restrict__ out) {
  const int gpt = blockIdx.x * BLOCK + threadIdx.x;
  if (gpt >= NP) return;

  float best = INFINITY;
  int bi = 0;
  for (int c = 0; c < NC; ++c) {
    float d = dbest[c * NP + gpt];
    if (d < best) { best = d; bi = ibest[c * NP + gpt]; }
  }

  const int batch = gpt / Q;
  const float px = pts[gpt * 3 + 0];
  const float py = pts[gpt * 3 + 1];
  const float pz = pts[gpt * 3 + 2];

  const float* tr = tris + ((size_t)batch * F + bi) * 9;
  float rx, ry, rz;
  closest_pt(px, py, pz,
             tr[0], tr[1], tr[2], tr[3], tr[4], tr[5], tr[6], tr[7], tr[8],
             rx, ry, rz);

  out[OFF_DIST + gpt] = best;
  out[OFF_CP + gpt * 3 + 0] = rx;
  out[OFF_CP + gpt * 3 + 1] = ry;
  out[OFF_CP + gpt * 3 + 2] = rz;
  out[OFF_FACE + gpt] = (float)bi;
}

}  // namespace

extern "C" void kernel_launch(void* const* d_in, const int* in_sizes, int n_in,
                              void* d_out, int out_size, void* d_ws, size_t ws_size,
                              hipStream_t stream) {
  const float* tris = (const float*)d_in[0];
  const float* pts  = (const float*)d_in[1];
  float* out = (float*)d_out;

  const int gx = B * ((Q / P) / BLOCK);   // 64 blocks in x
  dim3 grid2((NP + BLOCK - 1) / BLOCK);

  constexpr size_t KEY16_BYTES = (size_t)16 * NP * sizeof(uint4);   // 8 MiB
  constexpr size_t NC16_BYTES  = (size_t)16 * NP * (sizeof(float) + sizeof(unsigned short));

  if (ws_size >= KEY16_BYTES) {
    uint4* keys = (uint4*)d_ws;
    bvh_screen<16><<<dim3(gx, 16), BLOCK, 0, stream>>>(tris, pts, keys);
    bvh_finish<16><<<grid2, BLOCK, 0, stream>>>(tris, pts, keys, out);
  } else if (ws_size >= NC16_BYTES) {
    float* dbest = (float*)d_ws;
    unsigned short* ibest = (unsigned short*)((char*)d_ws + (size_t)16 * NP * sizeof(float));
    bvh_partial_p2<16><<<dim3(gx, 16), BLOCK, 0, stream>>>(tris, pts, dbest, ibest);
    bvh_reduce<16><<<grid2, BLOCK, 0, stream>>>(tris, pts, dbest, ibest, out);
  } else {
    float* dbest = (float*)d_ws;
    unsigned short* ibest = (unsigned short*)((char*)d_ws + (size_t)8 * NP * sizeof(float));
    bvh_partial_p2<8><<<dim3(gx, 8), BLOCK, 0, stream>>>(tris, pts, dbest, ibest);
    bvh_reduce<8><<<grid2, BLOCK, 0, stream>>>(tris, pts, dbest, ibest, out);
  }
}

// Round 10
// 166.840 us; speedup vs baseline: 1.7655x; 1.1959x over previous
//
#include <hip/hip_runtime.h>
#include <math.h>

namespace {

typedef float v2f __attribute__((ext_vector_type(2)));

constexpr int B = 2;
constexpr int F = 4096;      // triangles per batch
constexpr int Q = 16384;     // points per batch
constexpr int NP = B * Q;    // 32768 total points
constexpr int BLOCK = 256;
constexpr int P4 = 4;        // points per lane in screen

// output layout in d_out (float32): dist [NP], closest [NP,3], faces [NP]
constexpr int OFF_DIST = 0;
constexpr int OFF_CP = NP;
constexpr int OFF_FACE = 4 * NP;

// ---------------- exact path (reference-bit-order, contract OFF) -----------

__device__ __forceinline__ float safediv(float num, float den) {
  #pragma clang fp contract(off)
  float d = (fabsf(den) > 1e-12f) ? den : 1.0f;
  return num / d;
}

__device__ __forceinline__ float clamp01(float x) {
  return fminf(fmaxf(x, 0.0f), 1.0f);
}

// Ericson region-based closest point on triangle, mirroring the JAX reference
// op-for-op (including the where/override order). Contract OFF inside.
__device__ __forceinline__ void closest_pt(
    float px, float py, float pz,
    float ax, float ay, float az,
    float bx, float by, float bz,
    float cx, float cy, float cz,
    float& rx, float& ry, float& rz) {
  #pragma clang fp contract(off)
  float abx = bx - ax, aby = by - ay, abz = bz - az;
  float acx = cx - ax, acy = cy - ay, acz = cz - az;
  float apx = px - ax, apy = py - ay, apz = pz - az;
  float d1 = (abx * apx + aby * apy) + abz * apz;
  float d2 = (acx * apx + acy * apy) + acz * apz;
  float bpx = px - bx, bpy = py - by, bpz = pz - bz;
  float d3 = (abx * bpx + aby * bpy) + abz * bpz;
  float d4 = (acx * bpx + acy * bpy) + acz * bpz;
  float cpx = px - cx, cpy = py - cy, cpz = pz - cz;
  float d5 = (abx * cpx + aby * cpy) + abz * cpz;
  float d6 = (acx * cpx + acy * cpy) + acz * cpz;

  float vc = d1 * d4 - d3 * d2;
  float vb = d5 * d2 - d1 * d6;
  float va = d3 * d6 - d5 * d4;

  float v_ab = clamp01(safediv(d1, d1 - d3));
  float w_ac = clamp01(safediv(d2, d2 - d6));
  float w_bc = clamp01(safediv(d4 - d3, (d4 - d3) + (d5 - d6)));

  float denom = (va + vb) + vc;
  float v = safediv(vb, denom);
  float w = safediv(vc, denom);

  float ox = ax + abx * v + acx * w;
  float oy = ay + aby * v + acy * w;
  float oz = az + abz * v + acz * w;

  bool m_bc = (va <= 0.0f) && (d4 - d3 >= 0.0f) && (d5 - d6 >= 0.0f);
  bool m_ac = (vb <= 0.0f) && (d2 >= 0.0f) && (d6 <= 0.0f);
  bool m_ab = (vc <= 0.0f) && (d1 >= 0.0f) && (d3 <= 0.0f);
  bool m_c  = (d6 >= 0.0f) && (d5 <= d6);
  bool m_b  = (d3 >= 0.0f) && (d4 <= d3);
  bool m_a  = (d1 <= 0.0f) && (d2 <= 0.0f);

  if (m_bc) { ox = bx + w_bc * (cx - bx); oy = by + w_bc * (cy - by); oz = bz + w_bc * (cz - bz); }
  if (m_ac) { ox = ax + w_ac * acx;       oy = ay + w_ac * acy;       oz = az + w_ac * acz; }
  if (m_ab) { ox = ax + v_ab * abx;       oy = ay + v_ab * aby;       oz = az + v_ab * abz; }
  if (m_c)  { ox = cx; oy = cy; oz = cz; }
  if (m_b)  { ox = bx; oy = by; oz = bz; }
  if (m_a)  { ox = ax; oy = ay; oz = az; }

  rx = ox; ry = oy; rz = oz;
}

__device__ __forceinline__ float exact_d2(
    float px, float py, float pz, const float* __restrict__ g /*a,b,c*/) {
  #pragma clang fp contract(off)
  float rx, ry, rz;
  closest_pt(px, py, pz,
             g[0], g[1], g[2], g[3], g[4], g[5], g[6], g[7], g[8],
             rx, ry, rz);
  float dx = px - rx, dy = py - ry, dz = pz - rz;
  return (dx * dx + dy * dy) + dz * dz;
}

// ---------------- key helpers ----------------------------------------------

__device__ __forceinline__ unsigned umin2(unsigned a, unsigned b) { return a < b ? a : b; }
__device__ __forceinline__ unsigned umax2(unsigned a, unsigned b) { return a > b ? a : b; }

// sorted top-2 insert via min/max (3 VOP2 ops)
__device__ __forceinline__ void ins2(unsigned k, unsigned& K1, unsigned& K2) {
  unsigned t = umax2(K1, k);
  K1 = umin2(K1, k);
  K2 = umin2(K2, t);
}

// sorted top-8 insert via min/max network (15 ops)
__device__ __forceinline__ void ins8(unsigned k,
    unsigned& K1, unsigned& K2, unsigned& K3, unsigned& K4,
    unsigned& K5, unsigned& K6, unsigned& K7, unsigned& K8) {
  unsigned t;
  t = umax2(K1, k); K1 = umin2(K1, k);
  k = t; t = umax2(K2, k); K2 = umin2(K2, k);
  k = t; t = umax2(K3, k); K3 = umin2(K3, k);
  k = t; t = umax2(K4, k); K4 = umin2(K4, k);
  k = t; t = umax2(K5, k); K5 = umin2(K5, k);
  k = t; t = umax2(K6, k); K6 = umin2(K6, k);
  k = t; t = umax2(K7, k); K7 = umin2(K7, k);
  K8 = umin2(K8, t);
}

// ---------------- screen: P=4 points/lane, packed fp32 ---------------------
// LDS record (20 floats = 5 quads):
//  R0=[abx,aby,abz,c1] R1=[acx,acy,acz,c2] R2=[-2ax,-2ay,-2az,|a|^2]
//  R3=[aa,bb,abac,cc]  R4=[raa,rbb,rcc,rdn]
// Screen works on d^2 - |p|^2 (affine in p); |p|^2 restored before key pack.

// scalar finish of one point: returns packed key
__device__ __forceinline__ unsigned fin_one(
    float dint, float tabm, float tacm, float tbcm,
    float td1, float td2, float ap2m, float bp2, float t43d,
    float va, float vb, float vc,
    float aa, float bb, float cc, float pp, int gidx) {
  float tab = __builtin_amdgcn_fmed3f(tabm, 0.0f, 1.0f);
  float sab = fmaf(-tab, fmaf(-tab, aa, td1), ap2m);
  float tac = __builtin_amdgcn_fmed3f(tacm, 0.0f, 1.0f);
  float sac = fmaf(-tac, fmaf(-tac, bb, td2), ap2m);
  float tbc = __builtin_amdgcn_fmed3f(tbcm, 0.0f, 1.0f);
  float sbc = fmaf(-tbc, fmaf(-tbc, cc, t43d), bp2);
  float dseg = fminf(fminf(sab, sac), sbc);        // v_min3
  float mv   = fminf(fminf(va, vb), vc);           // v_min3
  float d = (mv > 0.0f) ? dint : dseg;
  d = fmaxf(d + pp, 0.0f);                         // restore |p|^2, keep >=0
  return (__float_as_uint(d) & 0xFFFFF000u) | (unsigned)gidx;
}

template <int NC>
__global__ __launch_bounds__(BLOCK, 4) void bvh_screen4(
    const float* __restrict__ tris,   // [B, F, 3, 3]
    const float* __restrict__ pts,    // [B, Q, 3]
    uint2* __restrict__ keys) {       // [NC, NP]
  constexpr int CFL = F / NC;         // 128
  __shared__ float4 s_rec[5 * CFL];   // 10 KiB

  constexpr int BPB = (Q / P4) / BLOCK;          // 16
  const int batch = blockIdx.x / BPB;            // uniform per block
  const int j = (blockIdx.x % BPB) * BLOCK + threadIdx.x;  // 0 .. Q/4-1
  const int chunk = blockIdx.y;
  const int tri0 = chunk * CFL;
  const float* tb = tris + (size_t)batch * F * 9;

  for (int t = threadIdx.x; t < CFL; t += BLOCK) {
    const float* g = tb + (size_t)(tri0 + t) * 9;
    float ax = g[0], ay = g[1], az = g[2];
    float abx = g[3] - ax, aby = g[4] - ay, abz = g[5] - az;
    float acx = g[6] - ax, acy = g[7] - ay, acz = g[8] - az;
    float aa   = abx * abx + aby * aby + abz * abz;
    float bb   = acx * acx + acy * acy + acz * acz;
    float abac = abx * acx + aby * acy + abz * acz;
    float bcx = acx - abx, bcy = acy - aby, bcz = acz - abz;
    float cc   = bcx * bcx + bcy * bcy + bcz * bcz;
    float nx = aby * acz - abz * acy;
    float ny = abz * acx - abx * acz;
    float nz = abx * acy - aby * acx;
    float n2 = nx * nx + ny * ny + nz * nz;
    float raa = (aa > 1e-12f) ? 1.0f / aa : 1.0f;     // safediv-style guards
    float rbb = (bb > 1e-12f) ? 1.0f / bb : 1.0f;
    float rcc = (cc > 1e-12f) ? 1.0f / cc : 1.0f;
    float rdn = (n2 > 1e-12f) ? 1.0f / n2 : 1.0f;
    float c1 = -(ax * abx + ay * aby + az * abz);
    float c2 = -(ax * acx + ay * acy + az * acz);
    float caa2 = ax * ax + ay * ay + az * az;
    s_rec[0 * CFL + t] = make_float4(abx, aby, abz, c1);
    s_rec[1 * CFL + t] = make_float4(acx, acy, acz, c2);
    s_rec[2 * CFL + t] = make_float4(-2.0f * ax, -2.0f * ay, -2.0f * az, caa2);
    s_rec[3 * CFL + t] = make_float4(aa, bb, abac, cc);
    s_rec[4 * CFL + t] = make_float4(raa, rbb, rcc, rdn);
  }
  __syncthreads();

  // four points per lane, Q/4 apart (same batch)
  const int p0 = batch * Q + j;
  float px0 = pts[(p0          ) * 3 + 0], py0 = pts[(p0          ) * 3 + 1], pz0 = pts[(p0          ) * 3 + 2];
  float px1 = pts[(p0 + Q/4    ) * 3 + 0], py1 = pts[(p0 + Q/4    ) * 3 + 1], pz1 = pts[(p0 + Q/4    ) * 3 + 2];
  float px2 = pts[(p0 + Q/2    ) * 3 + 0], py2 = pts[(p0 + Q/2    ) * 3 + 1], pz2 = pts[(p0 + Q/2    ) * 3 + 2];
  float px3 = pts[(p0 + 3*(Q/4)) * 3 + 0], py3 = pts[(p0 + 3*(Q/4)) * 3 + 1], pz3 = pts[(p0 + 3*(Q/4)) * 3 + 2];

  const v2f pxA = {px0, px1}, pyA = {py0, py1}, pzA = {pz0, pz1};
  const v2f pxB = {px2, px3}, pyB = {py2, py3}, pzB = {pz2, pz3};
  const float pp0 = px0*px0 + py0*py0 + pz0*pz0;
  const float pp1 = px1*px1 + py1*py1 + pz1*pz1;
  const float pp2 = px2*px2 + py2*py2 + pz2*pz2;
  const float pp3 = px3*px3 + py3*py3 + pz3*pz3;

  unsigned A1 = ~0u, A2 = ~0u, Bk1 = ~0u, Bk2 = ~0u;
  unsigned C1 = ~0u, C2 = ~0u, D1 = ~0u, D2 = ~0u;

  {
    #pragma clang fp contract(fast)
    for (int t = 0; t < CFL; ++t) {
      const float4 R0 = s_rec[0 * CFL + t];   // uniform addr -> broadcast
      const float4 R1 = s_rec[1 * CFL + t];
      const float4 R2 = s_rec[2 * CFL + t];
      const float4 R3 = s_rec[3 * CFL + t];
      const float4 R4 = s_rec[4 * CFL + t];
      const int gidx = tri0 + t;

      // ---- pair A (points 0,1), packed fp32 ----
      {
        v2f d1   = pxA * R0.x + pyA * R0.y + pzA * R0.z + R0.w;
        v2f d2   = pxA * R1.x + pyA * R1.y + pzA * R1.z + R1.w;
        v2f ap2m = pxA * R2.x + pyA * R2.y + pzA * R2.z + R2.w;
        v2f d3 = d1 - R3.x, d6 = d2 - R3.y, d4 = d2 - R3.z, d5 = d1 - R3.z;
        v2f t43 = d4 - d3;
        v2f va = d3 * d6 - d5 * d4;
        v2f vb = d5 * d2 - d1 * d6;
        v2f vc = d1 * d4 - d3 * d2;
        v2f td1 = d1 + d1, td2 = d2 + d2;
        v2f v = vb * R4.w, w = vc * R4.w;
        v2f h1 = v * R3.x + (w * R3.z - td1);
        v2f h2 = w * R3.y + (v * R3.z - td2);
        v2f dint = ap2m + (v * h1 + w * h2);
        v2f tabm = d1 * R4.x, tacm = d2 * R4.y, tbcm = t43 * R4.z;
        v2f bp2 = (ap2m - td1) + R3.x;
        v2f t43d = t43 + t43;
        ins2(fin_one(dint.x, tabm.x, tacm.x, tbcm.x, td1.x, td2.x, ap2m.x,
                     bp2.x, t43d.x, va.x, vb.x, vc.x,
                     R3.x, R3.y, R3.w, pp0, gidx), A1, A2);
        ins2(fin_one(dint.y, tabm.y, tacm.y, tbcm.y, td1.y, td2.y, ap2m.y,
                     bp2.y, t43d.y, va.y, vb.y, vc.y,
                     R3.x, R3.y, R3.w, pp1, gidx), Bk1, Bk2);
      }
      // ---- pair B (points 2,3), packed fp32 ----
      {
        v2f d1   = pxB * R0.x + pyB * R0.y + pzB * R0.z + R0.w;
        v2f d2   = pxB * R1.x + pyB * R1.y + pzB * R1.z + R1.w;
        v2f ap2m = pxB * R2.x + pyB * R2.y + pzB * R2.z + R2.w;
        v2f d3 = d1 - R3.x, d6 = d2 - R3.y, d4 = d2 - R3.z, d5 = d1 - R3.z;
        v2f t43 = d4 - d3;
        v2f va = d3 * d6 - d5 * d4;
        v2f vb = d5 * d2 - d1 * d6;
        v2f vc = d1 * d4 - d3 * d2;
        v2f td1 = d1 + d1, td2 = d2 + d2;
        v2f v = vb * R4.w, w = vc * R4.w;
        v2f h1 = v * R3.x + (w * R3.z - td1);
        v2f h2 = w * R3.y + (v * R3.z - td2);
        v2f dint = ap2m + (v * h1 + w * h2);
        v2f tabm = d1 * R4.x, tacm = d2 * R4.y, tbcm = t43 * R4.z;
        v2f bp2 = (ap2m - td1) + R3.x;
        v2f t43d = t43 + t43;
        ins2(fin_one(dint.x, tabm.x, tacm.x, tbcm.x, td1.x, td2.x, ap2m.x,
                     bp2.x, t43d.x, va.x, vb.x, vc.x,
                     R3.x, R3.y, R3.w, pp2, gidx), C1, C2);
        ins2(fin_one(dint.y, tabm.y, tacm.y, tbcm.y, td1.y, td2.y, ap2m.y,
                     bp2.y, t43d.y, va.y, vb.y, vc.y,
                     R3.x, R3.y, R3.w, pp3, gidx), D1, D2);
      }
    }
  }

  keys[(size_t)chunk * NP + p0            ] = make_uint2(A1, A2);
  keys[(size_t)chunk * NP + p0 + Q/4      ] = make_uint2(Bk1, Bk2);
  keys[(size_t)chunk * NP + p0 + Q/2      ] = make_uint2(C1, C2);
  keys[(size_t)chunk * NP + p0 + 3*(Q/4)  ] = make_uint2(D1, D2);
}

// ---------------- finish: merge 2*NC keys -> top-8 -> exact ----------------

template <int NC>
__global__ __launch_bounds__(BLOCK) void bvh_finish2(
    const float* __restrict__ tris,
    const float* __restrict__ pts,
    const uint2* __restrict__ keys,
    float* __restrict__ out) {
  const int gpt = blockIdx.x * BLOCK + threadIdx.x;
  if (gpt >= NP) return;

  unsigned K1 = ~0u, K2 = ~0u, K3 = ~0u, K4 = ~0u;
  unsigned K5 = ~0u, K6 = ~0u, K7 = ~0u, K8 = ~0u;
  for (int c = 0; c < NC; ++c) {
    uint2 k = keys[(size_t)c * NP + gpt];
    ins8(k.x, K1, K2, K3, K4, K5, K6, K7, K8);
    ins8(k.y, K1, K2, K3, K4, K5, K6, K7, K8);
  }

  const int batch = gpt / Q;
  const float* tb = tris + (size_t)batch * F * 9;
  const float px = pts[gpt * 3 + 0];
  const float py = pts[gpt * 3 + 1];
  const float pz = pts[gpt * 3 + 2];

  // order-independent first-occurrence argmin over the 8 candidates
  float be = INFINITY;
  int bi = 0x7FFFFFFF;
  #define CAND(Kx) { int t_ = (int)(Kx & 0xFFFu); \
    float d_ = exact_d2(px, py, pz, tb + (size_t)t_ * 9); \
    if (d_ < be || (d_ == be && t_ < bi)) { be = d_; bi = t_; } }
  CAND(K1) CAND(K2) CAND(K3) CAND(K4) CAND(K5) CAND(K6) CAND(K7) CAND(K8)
  #undef CAND

  const float* tr = tb + (size_t)bi * 9;
  float rx, ry, rz;
  closest_pt(px, py, pz,
             tr[0], tr[1], tr[2], tr[3], tr[4], tr[5], tr[6], tr[7], tr[8],
             rx, ry, rz);

  out[OFF_DIST + gpt] = be;
  out[OFF_CP + gpt * 3 + 0] = rx;
  out[OFF_CP + gpt * 3 + 1] = ry;
  out[OFF_CP + gpt * 3 + 2] = rz;
  out[OFF_FACE + gpt] = (float)bi;
}

// ---------------- fallback (ws < 8 MiB): round-8 proven path ---------------

__device__ __forceinline__ float screen_d2_sc(
    float px, float py, float pz,
    float ax, float ay, float az,
    float abx, float aby, float abz,
    float acx, float acy, float acz,
    float aa, float bb, float abac,
    float raa, float rbb, float rcc, float rdn) {
  #pragma clang fp contract(fast)
  float apx = px - ax, apy = py - ay, apz = pz - az;
  float ap2 = fmaf(apx, apx, fmaf(apy, apy, apz * apz));
  float d1  = fmaf(apx, abx, fmaf(apy, aby, apz * abz));
  float d2  = fmaf(apx, acx, fmaf(apy, acy, apz * acz));
  float d3 = d1 - aa, d6 = d2 - bb, d4 = d2 - abac, d5 = d1 - abac;
  float t43 = d4 - d3, t56 = d5 - d6;
  float va = d3 * d6 - d5 * d4;
  float vb = d5 * d2 - d1 * d6;
  float vc = d1 * d4 - d3 * d2;
  float td1 = d1 + d1, td2 = d2 + d2;
  float v = vb * rdn, w = vc * rdn;
  float h1 = fmaf(v, aa, fmaf(w, abac, -td1));
  float h2 = fmaf(w, bb, fmaf(v, abac, -td2));
  float dint = ap2 + fmaf(v, h1, w * h2);
  float tab = __builtin_amdgcn_fmed3f(d1 * raa, 0.0f, 1.0f);
  float sab = fmaf(-tab, fmaf(-tab, aa, td1), ap2);
  float tac = __builtin_amdgcn_fmed3f(d2 * rbb, 0.0f, 1.0f);
  float sac = fmaf(-tac, fmaf(-tac, bb, td2), ap2);
  float cc  = t43 + t56;
  float bp2 = (ap2 - td1) + aa;
  float tbc = __builtin_amdgcn_fmed3f(t43 * rcc, 0.0f, 1.0f);
  float sbc = fmaf(-tbc, fmaf(-tbc, cc, t43 + t43), bp2);
  float dseg = fminf(fminf(sab, sac), sbc);
  float mv   = fminf(fminf(va, vb), vc);
  float d = (mv > 0.0f) ? dint : dseg;
  return fmaxf(d, 0.0f);
}

__device__ __forceinline__ void ins4c(unsigned key,
    unsigned& K1, unsigned& K2, unsigned& K3, unsigned& K4) {
  bool b1 = key < K1, b2 = key < K2, b3 = key < K3, b4 = key < K4;
  K4 = b3 ? K3 : (b4 ? key : K4);
  K3 = b2 ? K2 : (b3 ? key : K3);
  K2 = b1 ? K1 : (b2 ? key : K2);
  K1 = b1 ? key : K1;
}

__device__ __forceinline__ void tail4(
    const float* __restrict__ tb, int tri0,
    float px, float py, float pz,
    unsigned K1, unsigned K2, unsigned K3, unsigned K4,
    float& be, int& bi) {
  int c0 = (int)(K1 & 0x1FFu), c1 = (int)(K2 & 0x1FFu);
  int c2 = (int)(K3 & 0x1FFu), c3 = (int)(K4 & 0x1FFu);
  int tmp;
  if (c0 > c1) { tmp = c0; c0 = c1; c1 = tmp; }
  if (c2 > c3) { tmp = c2; c2 = c3; c3 = tmp; }
  if (c0 > c2) { tmp = c0; c0 = c2; c2 = tmp; }
  if (c1 > c3) { tmp = c1; c1 = c3; c3 = tmp; }
  if (c1 > c2) { tmp = c1; c1 = c2; c2 = tmp; }
  be = exact_d2(px, py, pz, tb + (size_t)(tri0 + c0) * 9);
  bi = c0;
  { float d = exact_d2(px, py, pz, tb + (size_t)(tri0 + c1) * 9);
    if (d < be) { be = d; bi = c1; } }
  { float d = exact_d2(px, py, pz, tb + (size_t)(tri0 + c2) * 9);
    if (d < be) { be = d; bi = c2; } }
  { float d = exact_d2(px, py, pz, tb + (size_t)(tri0 + c3) * 9);
    if (d < be) { be = d; bi = c3; } }
}

template <int NC>
__global__ __launch_bounds__(BLOCK, 4) void bvh_partial_p2(
    const float* __restrict__ tris,
    const float* __restrict__ pts,
    float* __restrict__ dbest,
    unsigned short* __restrict__ ibest) {
  constexpr int CFL = F / NC;
  __shared__ float4 s_rec[4 * CFL];

  constexpr int BPB = (Q / 2) / BLOCK;
  const int batch = blockIdx.x / BPB;
  const int j = (blockIdx.x % BPB) * BLOCK + threadIdx.x;
  const int chunk = blockIdx.y;
  const int tri0 = chunk * CFL;
  const float* tb = tris + (size_t)batch * F * 9;

  for (int t = threadIdx.x; t < CFL; t += BLOCK) {
    const float* g = tb + (size_t)(tri0 + t) * 9;
    float ax = g[0], ay = g[1], az = g[2];
    float abx = g[3] - ax, aby = g[4] - ay, abz = g[5] - az;
    float acx = g[6] - ax, acy = g[7] - ay, acz = g[8] - az;
    float aa   = abx * abx + aby * aby + abz * abz;
    float bb   = acx * acx + acy * acy + acz * acz;
    float abac = abx * acx + aby * acy + abz * acz;
    float bcx = acx - abx, bcy = acy - aby, bcz = acz - abz;
    float cc   = bcx * bcx + bcy * bcy + bcz * bcz;
    float nx = aby * acz - abz * acy;
    float ny = abz * acx - abx * acz;
    float nz = abx * acy - aby * acx;
    float n2 = nx * nx + ny * ny + nz * nz;
    float raa = (aa > 1e-12f) ? 1.0f / aa : 1.0f;
    float rbb = (bb > 1e-12f) ? 1.0f / bb : 1.0f;
    float rcc = (cc > 1e-12f) ? 1.0f / cc : 1.0f;
    float rdn = (n2 > 1e-12f) ? 1.0f / n2 : 1.0f;
    s_rec[0 * CFL + t] = make_float4(ax, ay, az, abx);
    s_rec[1 * CFL + t] = make_float4(aby, abz, acx, acy);
    s_rec[2 * CFL + t] = make_float4(acz, aa, bb, abac);
    s_rec[3 * CFL + t] = make_float4(raa, rbb, rcc, rdn);
  }
  __syncthreads();

  const int p0 = batch * Q + j;
  const int p1 = p0 + Q / 2;
  const float px0 = pts[p0 * 3 + 0], py0 = pts[p0 * 3 + 1], pz0 = pts[p0 * 3 + 2];
  const float px1 = pts[p1 * 3 + 0], py1 = pts[p1 * 3 + 1], pz1 = pts[p1 * 3 + 2];

  unsigned A1 = ~0u, A2 = ~0u, A3 = ~0u, A4 = ~0u;
  unsigned B1 = ~0u, B2 = ~0u, B3 = ~0u, B4 = ~0u;

  for (int t = 0; t < CFL; ++t) {
    const float4 R0 = s_rec[0 * CFL + t];
    const float4 R1 = s_rec[1 * CFL + t];
    const float4 R2 = s_rec[2 * CFL + t];
    const float4 R3 = s_rec[3 * CFL + t];
    float ax = R0.x, ay = R0.y, az = R0.z, abx = R0.w;
    float aby = R1.x, abz = R1.y, acx = R1.z, acy = R1.w;
    float acz = R2.x, aa = R2.y, bb = R2.z, abac = R2.w;
    float raa = R3.x, rbb = R3.y, rcc = R3.z, rdn = R3.w;

    float d0 = screen_d2_sc(px0, py0, pz0, ax, ay, az, abx, aby, abz,
                            acx, acy, acz, aa, bb, abac, raa, rbb, rcc, rdn);
    ins4c((__float_as_uint(d0) & 0xFFFFFE00u) | (unsigned)t, A1, A2, A3, A4);
    float d1 = screen_d2_sc(px1, py1, pz1, ax, ay, az, abx, aby, abz,
                            acx, acy, acz, aa, bb, abac, raa, rbb, rcc, rdn);
    ins4c((__float_as_uint(d1) & 0xFFFFFE00u) | (unsigned)t, B1, B2, B3, B4);
  }

  float be0, be1;
  int bi0, bi1;
  tail4(tb, tri0, px0, py0, pz0, A1, A2, A3, A4, be0, bi0);
  tail4(tb, tri0, px1, py1, pz1, B1, B2, B3, B4, be1, bi1);

  dbest[chunk * NP + p0] = be0;
  ibest[chunk * NP + p0] = (unsigned short)(tri0 + bi0);
  dbest[chunk * NP + p1] = be1;
  ibest[chunk * NP + p1] = (unsigned short)(tri0 + bi1);
}

template <int NC>
__global__ __launch_bounds__(BLOCK) void bvh_reduce(
    const float* __restrict__ tris,
    const float* __restrict__ pts,
    const float* __restrict__ dbest,
    const unsigned short* __restrict__ ibest,
    float* __restrict__ out) {
  const int gpt = blockIdx.x * BLOCK + threadIdx.x;
  if (gpt >= NP) return;

  float best = INFINITY;
  int bi = 0;
  for (int c = 0; c < NC; ++c) {
    float d = dbest[c * NP + gpt];
    if (d < best) { best = d; bi = ibest[c * NP + gpt]; }
  }

  const int batch = gpt / Q;
  const float px = pts[gpt * 3 + 0];
  const float py = pts[gpt * 3 + 1];
  const float pz = pts[gpt * 3 + 2];

  const float* tr = tris + ((size_t)batch * F + bi) * 9;
  float rx, ry, rz;
  closest_pt(px, py, pz,
             tr[0], tr[1], tr[2], tr[3], tr[4], tr[5], tr[6], tr[7], tr[8],
             rx, ry, rz);

  out[OFF_DIST + gpt] = best;
  out[OFF_CP + gpt * 3 + 0] = rx;
  out[OFF_CP + gpt * 3 + 1] = ry;
  out[OFF_CP + gpt * 3 + 2] = rz;
  out[OFF_FACE + gpt] = (float)bi;
}

}  // namespace

extern "C" void kernel_launch(void* const* d_in, const int* in_sizes, int n_in,
                              void* d_out, int out_size, void* d_ws, size_t ws_size,
                              hipStream_t stream) {
  const float* tris = (const float*)d_in[0];
  const float* pts  = (const float*)d_in[1];
  float* out = (float*)d_out;

  dim3 grid2((NP + BLOCK - 1) / BLOCK);

  constexpr int NC = 32;
  constexpr size_t KEY_BYTES = (size_t)NC * NP * sizeof(uint2);   // 8 MiB

  if (ws_size >= KEY_BYTES) {
    uint2* keys = (uint2*)d_ws;
    const int gx = B * ((Q / P4) / BLOCK);   // 32
    bvh_screen4<NC><<<dim3(gx, NC), BLOCK, 0, stream>>>(tris, pts, keys);
    bvh_finish2<NC><<<grid2, BLOCK, 0, stream>>>(tris, pts, keys, out);
  } else {
    // round-8 proven fallback (3 MiB)
    float* dbest = (float*)d_ws;
    unsigned short* ibest = (unsigned short*)((char*)d_ws + (size_t)8 * NP * sizeof(float));
    const int gx = B * ((Q / 2) / BLOCK);    // 64
    bvh_partial_p2<8><<<dim3(gx, 8), BLOCK, 0, stream>>>(tris, pts, dbest, ibest);
    bvh_reduce<8><<<grid2, BLOCK, 0, stream>>>(tris, pts, dbest, ibest, out);
  }
}